// Round 12
// baseline (113.256 us; speedup 1.0000x reference)
//
#include <hip/hip_runtime.h>
#include <math.h>

// Problem constants: B=4, S=2048, D_IN=1024, D_OUT=1024, E=8, K=2
#define TOKENS 8192
#define DIN    1024
#define DOUT   1024
#define NE     8
#define NWAVES 4096   // 512 blocks x 8 waves; wave w handles tokens w and w+NWAVES (parallel)

typedef float vf4 __attribute__((ext_vector_type(4)));

// R11 refinements + 2 PARALLEL tokens/wave: each gate ds_read_b128 feeds two
// FMAs (per-token gate LDS traffic 32KB -> 16KB, the dominant DS-pipe term),
// and dual accumulator sets give in-register ILP across every latency phase.
// 512 blocks x 512 threads = 4096 waves, 2 blocks/CU, 16 waves/CU (LDS 32KB,
// VGPR<=128 via bounds(512,4)).
__global__ __launch_bounds__(512, 4) void moe_fused(
    const float* __restrict__ x,             // [TOKENS][DIN]
    const float* __restrict__ gate_w,        // [NE][DIN]
    const float* __restrict__ gate_b,        // [NE]
    const float* __restrict__ expert_biases, // [NE]
    const float* __restrict__ expert_w,      // [NE][DOUT][DIN]
    const float* __restrict__ expert_b,      // [NE][DOUT]
    float* __restrict__ out,                 // [TOKENS][DOUT]
    float* __restrict__ out_idx) {           // [TOKENS][2] (indices as f32)
  __shared__ float lgate[NE * DIN];  // 32 KB f32 (selection must be f32-exact)

  {
    const vf4* src = (const vf4*)gate_w;
    vf4* dst = (vf4*)lgate;
#pragma unroll
    for (int i = 0; i < 4; ++i)
      dst[threadIdx.x + 512 * i] = src[threadIdx.x + 512 * i];
  }

  const int w    = blockIdx.x * 8 + (threadIdx.x >> 6);
  const int lane = threadIdx.x & 63;
  const int t0 = w;
  const int t1 = w + NWAVES;

  // wave-uniform gate biases (scalar loads), reused for both tokens
  float zbias[NE];
#pragma unroll
  for (int e = 0; e < NE; ++e) zbias[e] = gate_b[e] + expert_biases[e];

  // both x rows issued before the barrier: 8 loads in flight, latency hides
  // under the vmcnt(0)+s_barrier drain of __syncthreads
  vf4 xa[4], xb[4];
  const vf4* xr0 = (const vf4*)(x + (size_t)t0 * DIN);
  const vf4* xr1 = (const vf4*)(x + (size_t)t1 * DIN);
#pragma unroll
  for (int i = 0; i < 4; ++i) xa[i] = xr0[lane + 64 * i];
#pragma unroll
  for (int i = 0; i < 4; ++i) xb[i] = xr1[lane + 64 * i];

  __syncthreads();

  // ---- gate partials, stage-major: each LDS weight read feeds BOTH tokens ----
  float za[NE], zb[NE];
#pragma unroll
  for (int e = 0; e < NE; ++e) { za[e] = 0.f; zb[e] = 0.f; }
#pragma unroll
  for (int i = 0; i < 4; ++i) {
    vf4 wv[NE];
#pragma unroll
    for (int e = 0; e < NE; ++e)
      wv[e] = ((const vf4*)(lgate + e * DIN))[lane + 64 * i];
#pragma unroll
    for (int e = 0; e < NE; ++e) {
      za[e] += xa[i].x * wv[e].x + xa[i].y * wv[e].y + xa[i].z * wv[e].z + xa[i].w * wv[e].w;
      zb[e] += xb[i].x * wv[e].x + xb[i].y * wv[e].y + xb[i].z * wv[e].z + xb[i].w * wv[e].w;
    }
  }

  // ---- butterfly reduce, stage-major: 16 independent shuffles per stage ----
#pragma unroll
  for (int off = 32; off > 0; off >>= 1) {
    float ta[NE], tb[NE];
#pragma unroll
    for (int e = 0; e < NE; ++e) ta[e] = __shfl_xor(za[e], off, 64);
#pragma unroll
    for (int e = 0; e < NE; ++e) tb[e] = __shfl_xor(zb[e], off, 64);
#pragma unroll
    for (int e = 0; e < NE; ++e) { za[e] += ta[e]; zb[e] += tb[e]; }
  }
#pragma unroll
  for (int e = 0; e < NE; ++e) { za[e] += zbias[e]; zb[e] += zbias[e]; }

  // ---- top-2 per token (sigmoid monotone -> identical indices & tie order) ----
  int e0 = 0; float z0 = za[0];
#pragma unroll
  for (int e = 1; e < NE; ++e) if (za[e] > z0) { z0 = za[e]; e0 = e; }
  int e1 = (e0 == 0) ? 1 : 0; float z1 = za[e1];
#pragma unroll
  for (int e = 0; e < NE; ++e) if (e != e0 && za[e] > z1) { z1 = za[e]; e1 = e; }

  int f0 = 0; float y0 = zb[0];
#pragma unroll
  for (int e = 1; e < NE; ++e) if (zb[e] > y0) { y0 = zb[e]; f0 = e; }
  int f1 = (f0 == 0) ? 1 : 0; float y1 = zb[f1];
#pragma unroll
  for (int e = 0; e < NE; ++e) if (e != f0 && zb[e] > y1) { y1 = zb[e]; f1 = e; }

  if (lane == 0) {  // retire tiny index stores early
    out_idx[t0 * 2 + 0] = (float)e0;
    out_idx[t0 * 2 + 1] = (float)e1;
    out_idx[t1 * 2 + 0] = (float)f0;
    out_idx[t1 * 2 + 1] = (float)f1;
  }

  // ---- all 4 value rows (64 KB L2-hot set) issued together ----
  const vf4* ra0 = (const vf4*)(expert_w + (size_t)e0 * (DOUT * DIN));        // w[e0][0][:]
  const vf4* ra1 = (const vf4*)(expert_w + (size_t)e1 * (DOUT * DIN) + DIN);  // w[e1][1][:]
  const vf4* rb0 = (const vf4*)(expert_w + (size_t)f0 * (DOUT * DIN));
  const vf4* rb1 = (const vf4*)(expert_w + (size_t)f1 * (DOUT * DIN) + DIN);
  vf4 wa0[4], wa1[4], wb0[4], wb1[4];
#pragma unroll
  for (int i = 0; i < 4; ++i) {
    wa0[i] = ra0[lane + 64 * i];
    wa1[i] = ra1[lane + 64 * i];
    wb0[i] = rb0[lane + 64 * i];
    wb1[i] = rb1[lane + 64 * i];
  }
  float ba0 = expert_b[e0 * DOUT + 0];
  float ba1 = expert_b[e1 * DOUT + 1];
  float bb0 = expert_b[f0 * DOUT + 0];
  float bb1 = expert_b[f1 * DOUT + 1];

  // wave-uniform weights (overlap the value-row loads)
  float pa0 = 1.f / (1.f + expf(-z0));
  float pa1 = 1.f / (1.f + expf(-z1));
  float sa  = 1.f / (pa0 + pa1);
  float wA0 = pa0 * sa, wA1 = pa1 * sa;

  float pb0 = 1.f / (1.f + expf(-y0));
  float pb1 = 1.f / (1.f + expf(-y1));
  float sb  = 1.f / (pb0 + pb1);
  float wB0 = pb0 * sb, wB1 = pb1 * sb;

  // per-lane weighted partials, one butterfly each (stage-major pair)
  float ovA = 0.f, ovB = 0.f;
#pragma unroll
  for (int i = 0; i < 4; ++i) {
    float dA0 = xa[i].x * wa0[i].x + xa[i].y * wa0[i].y + xa[i].z * wa0[i].z + xa[i].w * wa0[i].w;
    float dA1 = xa[i].x * wa1[i].x + xa[i].y * wa1[i].y + xa[i].z * wa1[i].z + xa[i].w * wa1[i].w;
    float dB0 = xb[i].x * wb0[i].x + xb[i].y * wb0[i].y + xb[i].z * wb0[i].z + xb[i].w * wb0[i].w;
    float dB1 = xb[i].x * wb1[i].x + xb[i].y * wb1[i].y + xb[i].z * wb1[i].z + xb[i].w * wb1[i].w;
    ovA += dA0 * wA0 + dA1 * wA1;
    ovB += dB0 * wB0 + dB1 * wB1;
  }
#pragma unroll
  for (int off = 32; off > 0; off >>= 1) {
    float tA = __shfl_xor(ovA, off, 64);
    float tB = __shfl_xor(ovB, off, 64);
    ovA += tA; ovB += tB;
  }
  ovA += ba0 * wA0 + ba1 * wA1;
  ovB += bb0 * wB0 + bb1 * wB1;

  // ---- broadcast stores: both 4 KB rows ----
  vf4 vA = {ovA, ovA, ovA, ovA};
  vf4 vB = {ovB, ovB, ovB, ovB};
  vf4* oA = (vf4*)(out + (size_t)t0 * DOUT);
  vf4* oB = (vf4*)(out + (size_t)t1 * DOUT);
#pragma unroll
  for (int i = 0; i < 4; ++i) {
    oA[lane + 64 * i] = vA;
    oB[lane + 64 * i] = vB;
  }
}

extern "C" void kernel_launch(void* const* d_in, const int* in_sizes, int n_in,
                              void* d_out, int out_size, void* d_ws, size_t ws_size,
                              hipStream_t stream) {
  const float* x             = (const float*)d_in[0];
  const float* gate_w        = (const float*)d_in[1];
  const float* gate_b        = (const float*)d_in[2];
  const float* expert_biases = (const float*)d_in[3];
  const float* expert_w      = (const float*)d_in[4];
  const float* expert_b      = (const float*)d_in[5];

  float* out     = (float*)d_out;
  float* out_idx = out + (size_t)TOKENS * DOUT;  // second tuple output, flat-concatenated

  // 512 blocks x 512 threads (8 waves) x 2 parallel tokens/wave = 8192 tokens.
  moe_fused<<<dim3(512), dim3(512), 0, stream>>>(
      x, gate_w, gate_b, expert_biases, expert_w, expert_b, out, out_idx);
}